// Round 3
// baseline (482.123 us; speedup 1.0000x reference)
//
#include <hip/hip_runtime.h>
#include <hip/hip_bf16.h>

// Problem constants
#define BB 8
#define NN 128
#define CC 256
#define HFD 160
#define WFD 160
#define SS 7
#define REGION_OUT_ELEMS (8*128*256*49)   // 12,845,056

typedef short short8 __attribute__((ext_vector_type(8)));
typedef float f32x4  __attribute__((ext_vector_type(4)));

// ---------------------------------------------------------------------------
// K0: convert proj_w [o][c] fp32 -> bf16, row-major (A-operand friendly).
// ---------------------------------------------------------------------------
__global__ __launch_bounds__(256) void k0_convert_w(const float* __restrict__ W,
                                                    __hip_bfloat16* __restrict__ Wb) {
    int o = blockIdx.x;
    int c = threadIdx.x;
    Wb[o * CC + c] = __float2bfloat16(W[o * CC + c]);
}

// ---------------------------------------------------------------------------
// K1: fused transpose + row-cumsum (w-prefix only; NO h-cumsum pass needed —
// K3a sums rows directly).
//   in : fm[b][c][h][w]   (w fastest)
//   out: R[b][h][w][c]    (c fastest), R = cumsum of fm along w
// ---------------------------------------------------------------------------
__global__ __launch_bounds__(256) void k1_rowsum_transpose(const float* __restrict__ fm,
                                                           float* __restrict__ R) {
    int bid = blockIdx.x;            // ((b*160)+h)*4 + cq
    int cq  = bid & 3;
    int bh  = bid >> 2;
    int h   = bh % HFD;
    int b   = bh / HFD;
    int c0  = cq * 64;
    int t   = threadIdx.x;

    __shared__ float tile[64][161];
    __shared__ float segsum[64][5];

    #pragma unroll
    for (int it = 0; it < 10; ++it) {
        int vid = it * 256 + t;              // 0..2559
        int c_l = vid / 40;
        int wq  = vid - c_l * 40;            // float4 index within row
        f32x4 v = __builtin_nontemporal_load(
            (const f32x4*)(fm + (((size_t)(b * CC + c0 + c_l)) * HFD + h) * WFD + wq * 4));
        tile[c_l][wq * 4 + 0] = v.x;
        tile[c_l][wq * 4 + 1] = v.y;
        tile[c_l][wq * 4 + 2] = v.z;
        tile[c_l][wq * 4 + 3] = v.w;
    }
    __syncthreads();

    int seg = t >> 6;        // 0..3
    int row = t & 63;        // 0..63
    {
        float s = 0.f;
        int w0 = seg * 40;
        #pragma unroll 8
        for (int k = 0; k < 40; ++k) {
            s += tile[row][w0 + k];
            tile[row][w0 + k] = s;
        }
        segsum[row][seg] = s;
    }
    __syncthreads();
    if (t < 64) {
        float a0 = segsum[t][0];
        float a1 = a0 + segsum[t][1];
        float a2 = a1 + segsum[t][2];
        segsum[t][1] = a0;
        segsum[t][2] = a1;
        segsum[t][3] = a2;
    }
    __syncthreads();
    if (seg > 0) {
        float off = segsum[row][seg];
        int w0 = seg * 40;
        #pragma unroll 8
        for (int k = 0; k < 40; ++k) tile[row][w0 + k] += off;
    }
    __syncthreads();

    size_t obase = (((size_t)b * HFD + h) * WFD) * CC + c0;
    #pragma unroll
    for (int it = 0; it < 10; ++it) {
        int vid = it * 256 + t;
        int w   = vid >> 4;        // 0..159
        int cg  = vid & 15;        // c = 4*cg
        float4 o;
        o.x = tile[cg * 4 + 0][w];
        o.y = tile[cg * 4 + 1][w];
        o.z = tile[cg * 4 + 2][w];
        o.w = tile[cg * 4 + 3][w];
        *(float4*)(R + obase + (size_t)w * CC + cg * 4) = o;
    }
}

// ---------------------------------------------------------------------------
// K3a: row-walk gather. Per (b,n), thread = channel c. For each cell-row i,
// accumulate sum over rows r in [rs_i, re_i) of R[r][ce_j-1] - R[r][cs_j-1]
// in fp32 registers (7 accumulators live), divide by count, write bf16 to
// Pm[bn][cell][c]. No LDS, no barriers: occupancy/ILP-rich, R is L3-hot.
// i/j loops fully unrolled so rs/re/cs/ce index statically (regs not scratch).
// ---------------------------------------------------------------------------
__global__ __launch_bounds__(256) void k3a_gather(
        const float* __restrict__ R, const float* __restrict__ bboxes,
        const int* __restrict__ ih_p, const int* __restrict__ iw_p,
        __hip_bfloat16* __restrict__ Pm, float* __restrict__ out) {
    int bn = blockIdx.x;         // b*128 + n
    int b  = bn >> 7;
    int c  = threadIdx.x;

    float bx1 = bboxes[bn * 4 + 0];
    float by1 = bboxes[bn * 4 + 1];
    float bx2 = bboxes[bn * 4 + 2];
    float by2 = bboxes[bn * 4 + 3];
    float sx = (float)WFD / (float)iw_p[0];
    float sy = (float)HFD / (float)ih_p[0];

    int x1 = min(max((int)floorf(bx1 * sx), 0), WFD - 1);
    int y1 = min(max((int)floorf(by1 * sy), 0), HFD - 1);
    int x2 = min(max((int)floorf(bx2 * sx), x1 + 1), WFD);
    int y2 = min(max((int)floorf(by2 * sy), y1 + 1), HFD);
    int Lx = x2 - x1, Ly = y2 - y1;

    int rs[SS], re[SS], cR[SS], cL[SS];   // cR = ce-1 (>=0 always), cL = max(cs-1,0)
    float lm[SS];                          // 0.0 when cs-1 < 0 else 1.0
    float cw[SS];                          // column count (ce-cs)
    #pragma unroll
    for (int i = 0; i < SS; ++i) {
        rs[i] = y1 + (i * Ly) / SS;
        re[i] = y1 + ((i + 1) * Ly + SS - 1) / SS;
        int cs_ = x1 + (i * Lx) / SS;
        int ce_ = x1 + ((i + 1) * Lx + SS - 1) / SS;
        cR[i] = ce_ - 1;
        cL[i] = (cs_ - 1 >= 0) ? cs_ - 1 : 0;
        lm[i] = (cs_ - 1 >= 0) ? 1.f : 0.f;
        cw[i] = (float)(ce_ - cs_);
    }

    const float* Rb = R + (size_t)b * HFD * WFD * CC + c;
    __hip_bfloat16* pmb = Pm + (size_t)bn * 64 * CC;

    #pragma unroll
    for (int i = 0; i < SS; ++i) {
        float acc[SS];
        #pragma unroll
        for (int j = 0; j < SS; ++j) acc[j] = 0.f;

        #pragma unroll 2
        for (int r = rs[i]; r < re[i]; ++r) {
            const float* rowp = Rb + (size_t)(r * WFD) * CC;
            #pragma unroll
            for (int j = 0; j < SS; ++j) {
                float right = rowp[cR[j] * CC];
                float left  = rowp[cL[j] * CC] * lm[j];
                acc[j] += right - left;
            }
        }

        float rh = (float)(re[i] - rs[i]);
        #pragma unroll
        for (int j = 0; j < SS; ++j) {
            pmb[(i * SS + j) * CC + c] = __float2bfloat16(acc[j] / (rh * cw[j]));
        }
    }

    // zero pad cells 49..63
    {
        __hip_bfloat16 z = __float2bfloat16(0.f);
        #pragma unroll
        for (int r = 49; r < 64; ++r) pmb[r * CC + c] = z;
    }

    if (c == 0) {
        __builtin_nontemporal_store((bx2 - bx1) * (by2 - by1), &out[REGION_OUT_ELEMS + bn]);
    }
}

// ---------------------------------------------------------------------------
// K3b: GEMM-only. out[bn][o][cell] = sum_c W[o][c]*Pm[bn][cell][c] + bias[o].
// M=256 (o), N=64 (49 + pad), K=256. A,B frags loaded directly from global
// (both L2-hot). No LDS, no barriers.
// ---------------------------------------------------------------------------
__global__ __launch_bounds__(256) void k3b_gemm(
        const __hip_bfloat16* __restrict__ Wb, const __hip_bfloat16* __restrict__ Pm,
        const float* __restrict__ bias, float* __restrict__ out) {
    int bn = blockIdx.x;
    int t  = threadIdx.x;
    const int lane = t & 63;
    const int wv   = t >> 6;
    const int ln   = lane & 15;
    const int quad = lane >> 4;
    const int ob0  = wv * 64;

    const short* A  = (const short*)Wb;
    const short* Bm = (const short*)(Pm + (size_t)bn * 64 * CC);

    f32x4 z = {0.f, 0.f, 0.f, 0.f};
    f32x4 acc[4][4];
    #pragma unroll
    for (int mt = 0; mt < 4; ++mt)
        #pragma unroll
        for (int nt = 0; nt < 4; ++nt) acc[mt][nt] = z;

    #pragma unroll
    for (int k0 = 0; k0 < CC; k0 += 32) {
        short8 a[4], bf[4];
        #pragma unroll
        for (int mt = 0; mt < 4; ++mt)
            a[mt] = *(const short8*)(A + (ob0 + mt * 16 + ln) * CC + k0 + quad * 8);
        #pragma unroll
        for (int nt = 0; nt < 4; ++nt)
            bf[nt] = *(const short8*)(Bm + (nt * 16 + ln) * CC + k0 + quad * 8);
        #pragma unroll
        for (int mt = 0; mt < 4; ++mt)
            #pragma unroll
            for (int nt = 0; nt < 4; ++nt)
                acc[mt][nt] = __builtin_amdgcn_mfma_f32_16x16x32_bf16(a[mt], bf[nt], acc[mt][nt], 0, 0, 0);
    }

    // epilogue: D layout col(cell)=lane&15, row(o)=quad*4+reg
    size_t obase = (size_t)bn * CC * 49;
    #pragma unroll
    for (int mt = 0; mt < 4; ++mt) {
        f32x4 bv = *(const f32x4*)(bias + ob0 + mt * 16 + quad * 4);
        #pragma unroll
        for (int nt = 0; nt < 4; ++nt) {
            int cell = nt * 16 + ln;
            if (cell < 49) {
                #pragma unroll
                for (int reg = 0; reg < 4; ++reg) {
                    int o = ob0 + mt * 16 + quad * 4 + reg;
                    __builtin_nontemporal_store(acc[mt][nt][reg] + bv[reg],
                                                &out[obase + (size_t)o * 49 + cell]);
                }
            }
        }
    }
}

// ---------------------------------------------------------------------------
extern "C" void kernel_launch(void* const* d_in, const int* in_sizes, int n_in,
                              void* d_out, int out_size, void* d_ws, size_t ws_size,
                              hipStream_t stream) {
    const float* fm     = (const float*)d_in[0];
    const float* bboxes = (const float*)d_in[1];
    const float* W      = (const float*)d_in[2];
    const float* bias   = (const float*)d_in[3];
    const int*   ih     = (const int*)d_in[4];
    const int*   iw     = (const int*)d_in[5];
    float* out = (float*)d_out;

    __hip_bfloat16* Wb = (__hip_bfloat16*)d_ws;                   // 256*256 bf16 = 128 KB
    float* R = (float*)((char*)d_ws + (size_t)CC * CC * 2 + 256); // w-prefix sums, c-fastest
    R = (float*)(((uintptr_t)R + 1023) & ~(uintptr_t)1023);
    // Pm after R: 1024 * 64 * 256 bf16 = 33.5 MB
    __hip_bfloat16* Pm = (__hip_bfloat16*)((char*)R + (size_t)BB * HFD * WFD * CC * 4);
    Pm = (__hip_bfloat16*)(((uintptr_t)Pm + 1023) & ~(uintptr_t)1023);

    k0_convert_w<<<CC, 256, 0, stream>>>(W, Wb);
    k1_rowsum_transpose<<<BB * HFD * 4, 256, 0, stream>>>(fm, R);
    k3a_gather<<<BB * NN, 256, 0, stream>>>(R, bboxes, ih, iw, Pm, out);
    k3b_gemm<<<BB * NN, 256, 0, stream>>>(Wb, Pm, bias, out);
}

// Round 4
// 427.531 us; speedup vs baseline: 1.1277x; 1.1277x over previous
//
#include <hip/hip_runtime.h>
#include <hip/hip_bf16.h>

// Problem constants
#define BB 8
#define NN 128
#define CC 256
#define HFD 160
#define WFD 160
#define SS 7
#define REGION_OUT_ELEMS (8*128*256*49)   // 12,845,056

typedef short short8 __attribute__((ext_vector_type(8)));
typedef float f32x4  __attribute__((ext_vector_type(4)));

// ---------------------------------------------------------------------------
// K0: convert proj_w [o][c] fp32 -> bf16, row-major (A-operand friendly).
// ---------------------------------------------------------------------------
__global__ __launch_bounds__(256) void k0_convert_w(const float* __restrict__ W,
                                                    __hip_bfloat16* __restrict__ Wb) {
    int o = blockIdx.x;
    int c = threadIdx.x;
    Wb[o * CC + c] = __float2bfloat16(W[o * CC + c]);
}

// ---------------------------------------------------------------------------
// K1: fused transpose + row-cumsum.
//   in : fm[b][c][h][w]   (w fastest)
//   out: R[b][h][w][c]    (c fastest), R = cumsum of fm along w
// ---------------------------------------------------------------------------
__global__ __launch_bounds__(256) void k1_rowsum_transpose(const float* __restrict__ fm,
                                                           float* __restrict__ R) {
    int bid = blockIdx.x;            // ((b*160)+h)*4 + cq
    int cq  = bid & 3;
    int bh  = bid >> 2;
    int h   = bh % HFD;
    int b   = bh / HFD;
    int c0  = cq * 64;
    int t   = threadIdx.x;

    __shared__ float tile[64][161];
    __shared__ float segsum[64][5];

    #pragma unroll
    for (int it = 0; it < 10; ++it) {
        int vid = it * 256 + t;              // 0..2559
        int c_l = vid / 40;
        int wq  = vid - c_l * 40;            // float4 index within row
        f32x4 v = __builtin_nontemporal_load(
            (const f32x4*)(fm + (((size_t)(b * CC + c0 + c_l)) * HFD + h) * WFD + wq * 4));
        tile[c_l][wq * 4 + 0] = v.x;
        tile[c_l][wq * 4 + 1] = v.y;
        tile[c_l][wq * 4 + 2] = v.z;
        tile[c_l][wq * 4 + 3] = v.w;
    }
    __syncthreads();

    int seg = t >> 6;        // 0..3
    int row = t & 63;        // 0..63
    {
        float s = 0.f;
        int w0 = seg * 40;
        #pragma unroll 8
        for (int k = 0; k < 40; ++k) {
            s += tile[row][w0 + k];
            tile[row][w0 + k] = s;
        }
        segsum[row][seg] = s;
    }
    __syncthreads();
    if (t < 64) {
        float a0 = segsum[t][0];
        float a1 = a0 + segsum[t][1];
        float a2 = a1 + segsum[t][2];
        segsum[t][1] = a0;
        segsum[t][2] = a1;
        segsum[t][3] = a2;
    }
    __syncthreads();
    if (seg > 0) {
        float off = segsum[row][seg];
        int w0 = seg * 40;
        #pragma unroll 8
        for (int k = 0; k < 40; ++k) tile[row][w0 + k] += off;
    }
    __syncthreads();

    size_t obase = (((size_t)b * HFD + h) * WFD) * CC + c0;
    #pragma unroll
    for (int it = 0; it < 10; ++it) {
        int vid = it * 256 + t;
        int w   = vid >> 4;        // 0..159
        int cg  = vid & 15;        // c = 4*cg
        float4 o;
        o.x = tile[cg * 4 + 0][w];
        o.y = tile[cg * 4 + 1][w];
        o.z = tile[cg * 4 + 2][w];
        o.w = tile[cg * 4 + 3][w];
        *(float4*)(R + obase + (size_t)w * CC + cg * 4) = o;
    }
}

// ---------------------------------------------------------------------------
// K2: in-place column cumsum along h in c-fastest layout.
// One 256-thread WG per (b, w); thread owns ONE channel (scalar RMW).
// ---------------------------------------------------------------------------
__global__ __launch_bounds__(256) void k2_colsum(float* __restrict__ I) {
    int w = blockIdx.x % WFD;
    int b = blockIdx.x / WFD;
    int c = threadIdx.x;
    float* p = I + (((size_t)b * HFD) * WFD + w) * CC + c;   // h = 0
    const size_t stride = (size_t)WFD * CC;                   // per-h stride (floats)
    float s = 0.f;
    #pragma unroll 16
    for (int h = 0; h < HFD; ++h) {
        float v = p[(size_t)h * stride];
        s += v;
        p[(size_t)h * stride] = s;
    }
}

// ---------------------------------------------------------------------------
// K3: fused gather + GEMM, 512 threads (8 waves).
// Gather: wave wv computes "cells" wv+8k (k=0..6) -> 56 slots; slots 49..55
// duplicate cell 48 (their GEMM outputs are never stored). Lane owns 4
// channels (float4 loads, 1KB per wave-access). Branch-free: clamped corner
// indices + 0/1 mask multiplies -> 28 independent fat loads per lane, deep
// pipeline. Pb rows 56..63 left uninit (only feed discarded output columns).
// GEMM: wave wv owns o in [wv*32, wv*32+32): acc[2][4], 64 MFMA/wave.
// ---------------------------------------------------------------------------
#define PB_STRIDE 264   // bf16 elems; 528 B row

__global__ __launch_bounds__(512) void k3_gather_gemm(
        const float* __restrict__ I, const __hip_bfloat16* __restrict__ Wb,
        const float* __restrict__ bias, const float* __restrict__ bboxes,
        const int* __restrict__ ih_p, const int* __restrict__ iw_p,
        float* __restrict__ out) {
    int bn = blockIdx.x;         // b*128 + n
    int b  = bn >> 7;
    int t  = threadIdx.x;
    const int lane = t & 63;
    const int wv   = t >> 6;     // 0..7

    __shared__ __hip_bfloat16 Pb[64 * PB_STRIDE];   // 33 KB

    float bx1 = bboxes[bn * 4 + 0];
    float by1 = bboxes[bn * 4 + 1];
    float bx2 = bboxes[bn * 4 + 2];
    float by2 = bboxes[bn * 4 + 3];
    float sx = (float)WFD / (float)iw_p[0];
    float sy = (float)HFD / (float)ih_p[0];

    int x1 = min(max((int)floorf(bx1 * sx), 0), WFD - 1);
    int y1 = min(max((int)floorf(by1 * sy), 0), HFD - 1);
    int x2 = min(max((int)floorf(bx2 * sx), x1 + 1), WFD);
    int y2 = min(max((int)floorf(by2 * sy), y1 + 1), HFD);
    int Lx = x2 - x1, Ly = y2 - y1;

    // ---- gather phase: branch-free, float4 per lane ----
    {
        const float* Ibl = I + (size_t)b * HFD * WFD * CC + 4 * lane;
        unsigned short* pbs = (unsigned short*)Pb;

        #pragma unroll
        for (int k = 0; k < 7; ++k) {
            int cell = wv + 8 * k;           // 0..55, each exactly once
            int cc_  = min(cell, 48);        // slots 49..55 duplicate cell 48
            int i_ = cc_ / SS, j_ = cc_ % SS;

            int rs_ = y1 + (i_ * Ly) / SS;
            int re_ = y1 + ((i_ + 1) * Ly + SS - 1) / SS;
            int cs_ = x1 + (j_ * Lx) / SS;
            int ce_ = x1 + ((j_ + 1) * Lx + SS - 1) / SS;

            int r1 = re_ - 1;
            int r0 = max(rs_ - 1, 0);
            int c1 = ce_ - 1;
            int c0 = max(cs_ - 1, 0);
            float rm = (rs_ > 0) ? 1.f : 0.f;
            float cm = (cs_ > 0) ? 1.f : 0.f;

            f32x4 br = *(const f32x4*)(Ibl + ((size_t)(r1 * WFD + c1)) * CC);
            f32x4 tr = *(const f32x4*)(Ibl + ((size_t)(r0 * WFD + c1)) * CC);
            f32x4 bl = *(const f32x4*)(Ibl + ((size_t)(r1 * WFD + c0)) * CC);
            f32x4 tl = *(const f32x4*)(Ibl + ((size_t)(r0 * WFD + c0)) * CC);

            f32x4 s = (br - tr * rm) - (bl - tl * rm) * cm;
            float inv = 1.f / ((float)(re_ - rs_) * (float)(ce_ - cs_));

            ushort4 pk;
            {
                __hip_bfloat16 h0 = __float2bfloat16(s.x * inv);
                __hip_bfloat16 h1 = __float2bfloat16(s.y * inv);
                __hip_bfloat16 h2 = __float2bfloat16(s.z * inv);
                __hip_bfloat16 h3 = __float2bfloat16(s.w * inv);
                pk.x = *(unsigned short*)&h0;
                pk.y = *(unsigned short*)&h1;
                pk.z = *(unsigned short*)&h2;
                pk.w = *(unsigned short*)&h3;
            }
            *(ushort4*)(pbs + cell * PB_STRIDE + 4 * lane) = pk;
        }
    }
    __syncthreads();

    // ---- GEMM phase: wave wv owns o in [wv*32, wv*32+32) ----
    {
        const int ln   = lane & 15;
        const int quad = lane >> 4;
        const int ob0  = wv * 32;

        f32x4 z = {0.f, 0.f, 0.f, 0.f};
        f32x4 acc[2][4];
        #pragma unroll
        for (int mt = 0; mt < 2; ++mt)
            #pragma unroll
            for (int nt = 0; nt < 4; ++nt) acc[mt][nt] = z;

        const short* A = (const short*)Wb;
        #pragma unroll
        for (int k0 = 0; k0 < CC; k0 += 32) {
            short8 a[2], bf[4];
            #pragma unroll
            for (int mt = 0; mt < 2; ++mt)
                a[mt] = *(const short8*)(A + (ob0 + mt * 16 + ln) * CC + k0 + quad * 8);
            #pragma unroll
            for (int nt = 0; nt < 4; ++nt)
                bf[nt] = *(const short8*)((const short*)Pb + (nt * 16 + ln) * PB_STRIDE + k0 + quad * 8);
            #pragma unroll
            for (int mt = 0; mt < 2; ++mt)
                #pragma unroll
                for (int nt = 0; nt < 4; ++nt)
                    acc[mt][nt] = __builtin_amdgcn_mfma_f32_16x16x32_bf16(a[mt], bf[nt], acc[mt][nt], 0, 0, 0);
        }

        // epilogue: D layout col(cell)=lane&15, row(o)=quad*4+reg
        size_t obase = (size_t)bn * CC * 49;
        #pragma unroll
        for (int mt = 0; mt < 2; ++mt) {
            f32x4 bv = *(const f32x4*)(bias + ob0 + mt * 16 + quad * 4);
            #pragma unroll
            for (int nt = 0; nt < 4; ++nt) {
                int cell = nt * 16 + ln;
                if (cell < 49) {
                    #pragma unroll
                    for (int reg = 0; reg < 4; ++reg) {
                        int o = ob0 + mt * 16 + quad * 4 + reg;
                        __builtin_nontemporal_store(acc[mt][nt][reg] + bv[reg],
                                                    &out[obase + (size_t)o * 49 + cell]);
                    }
                }
            }
        }
    }

    if (t == 0) {
        __builtin_nontemporal_store((bx2 - bx1) * (by2 - by1), &out[REGION_OUT_ELEMS + bn]);
    }
}

// ---------------------------------------------------------------------------
extern "C" void kernel_launch(void* const* d_in, const int* in_sizes, int n_in,
                              void* d_out, int out_size, void* d_ws, size_t ws_size,
                              hipStream_t stream) {
    const float* fm     = (const float*)d_in[0];
    const float* bboxes = (const float*)d_in[1];
    const float* W      = (const float*)d_in[2];
    const float* bias   = (const float*)d_in[3];
    const int*   ih     = (const int*)d_in[4];
    const int*   iw     = (const int*)d_in[5];
    float* out = (float*)d_out;

    __hip_bfloat16* Wb = (__hip_bfloat16*)d_ws;                   // 256*256 bf16 = 128 KB
    float* I = (float*)((char*)d_ws + (size_t)CC * CC * 2 + 256); // integral image, c-fastest
    I = (float*)(((uintptr_t)I + 1023) & ~(uintptr_t)1023);

    k0_convert_w<<<CC, 256, 0, stream>>>(W, Wb);
    k1_rowsum_transpose<<<BB * HFD * 4, 256, 0, stream>>>(fm, I);
    k2_colsum<<<BB * WFD, 256, 0, stream>>>(I);
    k3_gather_gemm<<<BB * NN, 512, 0, stream>>>(I, Wb, bias, bboxes, ih, iw, out);
}

// Round 5
// 410.997 us; speedup vs baseline: 1.1731x; 1.0402x over previous
//
#include <hip/hip_runtime.h>
#include <hip/hip_bf16.h>

// Problem constants
#define BB 8
#define NN 128
#define CC 256
#define HFD 160
#define WFD 160
#define SS 7
#define REGION_OUT_ELEMS (8*128*256*49)   // 12,845,056

typedef short short8 __attribute__((ext_vector_type(8)));
typedef float f32x4  __attribute__((ext_vector_type(4)));

// ---------------------------------------------------------------------------
// K0: convert proj_w [o][c] fp32 -> bf16, row-major (A-operand friendly).
// ---------------------------------------------------------------------------
__global__ __launch_bounds__(256) void k0_convert_w(const float* __restrict__ W,
                                                    __hip_bfloat16* __restrict__ Wb) {
    int o = blockIdx.x;
    int c = threadIdx.x;
    Wb[o * CC + c] = __float2bfloat16(W[o * CC + c]);
}

// ---------------------------------------------------------------------------
// K1: fused transpose + row-cumsum.
//   in : fm[b][c][h][w]   (w fastest)
//   out: R[b][h][w][c]    (c fastest), R = cumsum of fm along w
// ---------------------------------------------------------------------------
__global__ __launch_bounds__(256) void k1_rowsum_transpose(const float* __restrict__ fm,
                                                           float* __restrict__ R) {
    int bid = blockIdx.x;            // ((b*160)+h)*4 + cq
    int cq  = bid & 3;
    int bh  = bid >> 2;
    int h   = bh % HFD;
    int b   = bh / HFD;
    int c0  = cq * 64;
    int t   = threadIdx.x;

    __shared__ float tile[64][161];
    __shared__ float segsum[64][5];

    #pragma unroll
    for (int it = 0; it < 10; ++it) {
        int vid = it * 256 + t;              // 0..2559
        int c_l = vid / 40;
        int wq  = vid - c_l * 40;            // float4 index within row
        f32x4 v = __builtin_nontemporal_load(
            (const f32x4*)(fm + (((size_t)(b * CC + c0 + c_l)) * HFD + h) * WFD + wq * 4));
        tile[c_l][wq * 4 + 0] = v.x;
        tile[c_l][wq * 4 + 1] = v.y;
        tile[c_l][wq * 4 + 2] = v.z;
        tile[c_l][wq * 4 + 3] = v.w;
    }
    __syncthreads();

    int seg = t >> 6;        // 0..3
    int row = t & 63;        // 0..63
    {
        float s = 0.f;
        int w0 = seg * 40;
        #pragma unroll 8
        for (int k = 0; k < 40; ++k) {
            s += tile[row][w0 + k];
            tile[row][w0 + k] = s;
        }
        segsum[row][seg] = s;
    }
    __syncthreads();
    if (t < 64) {
        float a0 = segsum[t][0];
        float a1 = a0 + segsum[t][1];
        float a2 = a1 + segsum[t][2];
        segsum[t][1] = a0;
        segsum[t][2] = a1;
        segsum[t][3] = a2;
    }
    __syncthreads();
    if (seg > 0) {
        float off = segsum[row][seg];
        int w0 = seg * 40;
        #pragma unroll 8
        for (int k = 0; k < 40; ++k) tile[row][w0 + k] += off;
    }
    __syncthreads();

    size_t obase = (((size_t)b * HFD + h) * WFD) * CC + c0;
    #pragma unroll
    for (int it = 0; it < 10; ++it) {
        int vid = it * 256 + t;
        int w   = vid >> 4;        // 0..159
        int cg  = vid & 15;        // c = 4*cg
        float4 o;
        o.x = tile[cg * 4 + 0][w];
        o.y = tile[cg * 4 + 1][w];
        o.z = tile[cg * 4 + 2][w];
        o.w = tile[cg * 4 + 3][w];
        *(float4*)(R + obase + (size_t)w * CC + cg * 4) = o;
    }
}

// ---------------------------------------------------------------------------
// K2: in-place column cumsum along h in c-fastest layout.
// One 256-thread WG per (b, w); thread owns ONE channel (scalar RMW).
// ---------------------------------------------------------------------------
__global__ __launch_bounds__(256) void k2_colsum(float* __restrict__ I) {
    int w = blockIdx.x % WFD;
    int b = blockIdx.x / WFD;
    int c = threadIdx.x;
    float* p = I + (((size_t)b * HFD) * WFD + w) * CC + c;   // h = 0
    const size_t stride = (size_t)WFD * CC;                   // per-h stride (floats)
    float s = 0.f;
    #pragma unroll 16
    for (int h = 0; h < HFD; ++h) {
        float v = p[(size_t)h * stride];
        s += v;
        p[(size_t)h * stride] = s;
    }
}

// ---------------------------------------------------------------------------
// K3: fused gather + GEMM, 512 threads (8 waves).
// bn swizzled so image b == XCD id (BB == 8 XCDs): per-XCD L2 gather working
// set drops 210 MB -> 26 MB.
// Gather: wave wv owns cells wv*6+k (k=0..5); wave 0 additionally cell 48.
// Exactly 49 cell-gathers (no duplicates). Pb rows 49..63 stale garbage --
// they only feed MFMA output columns that are never stored (columns are
// independent in a GEMM).
// GEMM: wave wv owns o in [wv*32, wv*32+32): acc[2][4], 64 MFMA/wave.
// Epilogue: stage o-halves (128 o x 49 cells, 25 KB) in Pb's LDS, then copy
// out with fully-coalesced f32x4 NT stores.
// ---------------------------------------------------------------------------
#define PB_STRIDE 264   // bf16 elems; 528 B row

__global__ __launch_bounds__(512) void k3_gather_gemm(
        const float* __restrict__ I, const __hip_bfloat16* __restrict__ Wb,
        const float* __restrict__ bias, const float* __restrict__ bboxes,
        const int* __restrict__ ih_p, const int* __restrict__ iw_p,
        float* __restrict__ out) {
    int bid = blockIdx.x;
    int bn  = ((bid & 7) << 7) | (bid >> 3);   // image = bid&7 -> one image per XCD
    int b   = bn >> 7;
    int t   = threadIdx.x;
    const int lane = t & 63;
    const int wv   = t >> 6;     // 0..7

    __shared__ __align__(16) __hip_bfloat16 Pb[64 * PB_STRIDE];   // 33 KB
    float* stage = (float*)Pb;   // reused after GEMM: 128 o x 49 cells = 25 KB

    float bx1 = bboxes[bn * 4 + 0];
    float by1 = bboxes[bn * 4 + 1];
    float bx2 = bboxes[bn * 4 + 2];
    float by2 = bboxes[bn * 4 + 3];
    float sx = (float)WFD / (float)iw_p[0];
    float sy = (float)HFD / (float)ih_p[0];

    int x1 = min(max((int)floorf(bx1 * sx), 0), WFD - 1);
    int y1 = min(max((int)floorf(by1 * sy), 0), HFD - 1);
    int x2 = min(max((int)floorf(bx2 * sx), x1 + 1), WFD);
    int y2 = min(max((int)floorf(by2 * sy), y1 + 1), HFD);
    int Lx = x2 - x1, Ly = y2 - y1;

    // ---- gather phase: branch-free fat loads, 49 cells exactly ----
    {
        const float* Ibl = I + (size_t)b * HFD * WFD * CC + 4 * lane;
        unsigned short* pbs = (unsigned short*)Pb;

#define GATHER_CELL(cellv)                                                       \
        {                                                                        \
            int cell = (cellv);                                                  \
            int i_ = cell / SS, j_ = cell % SS;                                  \
            int rs_ = y1 + (i_ * Ly) / SS;                                       \
            int re_ = y1 + ((i_ + 1) * Ly + SS - 1) / SS;                        \
            int cs_ = x1 + (j_ * Lx) / SS;                                       \
            int ce_ = x1 + ((j_ + 1) * Lx + SS - 1) / SS;                        \
            int r1 = re_ - 1;                                                    \
            int r0 = max(rs_ - 1, 0);                                            \
            int c1 = ce_ - 1;                                                    \
            int c0 = max(cs_ - 1, 0);                                            \
            float rm = (rs_ > 0) ? 1.f : 0.f;                                    \
            float cm = (cs_ > 0) ? 1.f : 0.f;                                    \
            f32x4 br = *(const f32x4*)(Ibl + ((size_t)(r1 * WFD + c1)) * CC);    \
            f32x4 tr = *(const f32x4*)(Ibl + ((size_t)(r0 * WFD + c1)) * CC);    \
            f32x4 bl = *(const f32x4*)(Ibl + ((size_t)(r1 * WFD + c0)) * CC);    \
            f32x4 tl = *(const f32x4*)(Ibl + ((size_t)(r0 * WFD + c0)) * CC);    \
            f32x4 s = (br - tr * rm) - (bl - tl * rm) * cm;                      \
            float inv = 1.f / ((float)(re_ - rs_) * (float)(ce_ - cs_));         \
            ushort4 pk;                                                          \
            {                                                                    \
                __hip_bfloat16 h0 = __float2bfloat16(s.x * inv);                 \
                __hip_bfloat16 h1 = __float2bfloat16(s.y * inv);                 \
                __hip_bfloat16 h2 = __float2bfloat16(s.z * inv);                 \
                __hip_bfloat16 h3 = __float2bfloat16(s.w * inv);                 \
                pk.x = *(unsigned short*)&h0;                                    \
                pk.y = *(unsigned short*)&h1;                                    \
                pk.z = *(unsigned short*)&h2;                                    \
                pk.w = *(unsigned short*)&h3;                                    \
            }                                                                    \
            *(ushort4*)(pbs + cell * PB_STRIDE + 4 * lane) = pk;                 \
        }

        #pragma unroll
        for (int k = 0; k < 6; ++k) GATHER_CELL(wv * 6 + k);
        if (wv == 0) GATHER_CELL(48);
#undef GATHER_CELL
    }
    __syncthreads();

    // ---- GEMM phase: wave wv owns o in [wv*32, wv*32+32) ----
    const int ln   = lane & 15;
    const int quad = lane >> 4;
    const int ob0  = wv * 32;

    f32x4 z = {0.f, 0.f, 0.f, 0.f};
    f32x4 acc[2][4];
    #pragma unroll
    for (int mt = 0; mt < 2; ++mt)
        #pragma unroll
        for (int nt = 0; nt < 4; ++nt) acc[mt][nt] = z;

    {
        const short* A = (const short*)Wb;
        #pragma unroll
        for (int k0 = 0; k0 < CC; k0 += 32) {
            short8 a[2], bf[4];
            #pragma unroll
            for (int mt = 0; mt < 2; ++mt)
                a[mt] = *(const short8*)(A + (ob0 + mt * 16 + ln) * CC + k0 + quad * 8);
            #pragma unroll
            for (int nt = 0; nt < 4; ++nt)
                bf[nt] = *(const short8*)((const short*)Pb + (nt * 16 + ln) * PB_STRIDE + k0 + quad * 8);
            #pragma unroll
            for (int mt = 0; mt < 2; ++mt)
                #pragma unroll
                for (int nt = 0; nt < 4; ++nt)
                    acc[mt][nt] = __builtin_amdgcn_mfma_f32_16x16x32_bf16(a[mt], bf[nt], acc[mt][nt], 0, 0, 0);
        }
    }

    // ---- epilogue: LDS-staged, coalesced f32x4 NT stores ----
    // D layout: col(cell)=lane&15 within nt-tile, row(o)=quad*4+reg.
    size_t obase = (size_t)bn * CC * 49;
    #pragma unroll
    for (int half = 0; half < 2; ++half) {
        __syncthreads();   // half0: GEMM reads of Pb done; half1: copy0 done
        if ((wv >> 2) == half) {
            int ob0l = (wv & 3) * 32;      // o offset within this half
            #pragma unroll
            for (int mt = 0; mt < 2; ++mt) {
                f32x4 bv = *(const f32x4*)(bias + ob0 + mt * 16 + quad * 4);
                #pragma unroll
                for (int nt = 0; nt < 4; ++nt) {
                    int cell = nt * 16 + ln;
                    if (cell < 49) {
                        #pragma unroll
                        for (int reg = 0; reg < 4; ++reg) {
                            int ol = ob0l + mt * 16 + quad * 4 + reg;
                            stage[ol * 49 + cell] = acc[mt][nt][reg] + bv[reg];
                        }
                    }
                }
            }
        }
        __syncthreads();
        const f32x4* sv = (const f32x4*)stage;
        float* gbase = out + obase + (size_t)half * (128 * 49);
        for (int i = t; i < (128 * 49) / 4; i += 512) {
            __builtin_nontemporal_store(sv[i], (f32x4*)(gbase + 4 * i));
        }
    }

    if (t == 0) {
        __builtin_nontemporal_store((bx2 - bx1) * (by2 - by1), &out[REGION_OUT_ELEMS + bn]);
    }
}

// ---------------------------------------------------------------------------
extern "C" void kernel_launch(void* const* d_in, const int* in_sizes, int n_in,
                              void* d_out, int out_size, void* d_ws, size_t ws_size,
                              hipStream_t stream) {
    const float* fm     = (const float*)d_in[0];
    const float* bboxes = (const float*)d_in[1];
    const float* W      = (const float*)d_in[2];
    const float* bias   = (const float*)d_in[3];
    const int*   ih     = (const int*)d_in[4];
    const int*   iw     = (const int*)d_in[5];
    float* out = (float*)d_out;

    __hip_bfloat16* Wb = (__hip_bfloat16*)d_ws;                   // 256*256 bf16 = 128 KB
    float* I = (float*)((char*)d_ws + (size_t)CC * CC * 2 + 256); // integral image, c-fastest
    I = (float*)(((uintptr_t)I + 1023) & ~(uintptr_t)1023);

    k0_convert_w<<<CC, 256, 0, stream>>>(W, Wb);
    k1_rowsum_transpose<<<BB * HFD * 4, 256, 0, stream>>>(fm, I);
    k2_colsum<<<BB * WFD, 256, 0, stream>>>(I);
    k3_gather_gemm<<<BB * NN, 512, 0, stream>>>(I, Wb, bias, bboxes, ih, iw, out);
}

// Round 6
// 395.979 us; speedup vs baseline: 1.2175x; 1.0379x over previous
//
#include <hip/hip_runtime.h>
#include <hip/hip_bf16.h>

// Problem constants
#define BB 8
#define NN 128
#define CC 256
#define HFD 160
#define WFD 160
#define SS 7
#define HB 8                 // h-block size for hierarchical integral
#define NHB (HFD / HB)       // 20 blocks
#define REGION_OUT_ELEMS (8*128*256*49)   // 12,845,056

typedef short short8 __attribute__((ext_vector_type(8)));
typedef float f32x4  __attribute__((ext_vector_type(4)));

// ---------------------------------------------------------------------------
// K0: convert proj_w [o][c] fp32 -> bf16, row-major (A-operand friendly).
// ---------------------------------------------------------------------------
__global__ __launch_bounds__(256) void k0_convert_w(const float* __restrict__ W,
                                                    __hip_bfloat16* __restrict__ Wb) {
    int o = blockIdx.x;
    int c = threadIdx.x;
    Wb[o * CC + c] = __float2bfloat16(W[o * CC + c]);
}

// ---------------------------------------------------------------------------
// K1': fused transpose + w-cumsum + WITHIN-8-ROW-BLOCK h-cumsum.
//   in : fm[b][c][h][w]   (w fastest)
//   out: Ip[b][h][w][c]   (c fastest); Ip = w-prefix + h-prefix within block
// WG owns (b, c-quarter, h-block of 8 rows); running column sum lives in
// 10 x f32x4 registers per thread (its 10 (w,cg) output slots).
// Replaces the old full-image K2 h-cumsum pass (-420 MB HBM).
// ---------------------------------------------------------------------------
__global__ __launch_bounds__(256) void k1_rowscan_block(const float* __restrict__ fm,
                                                        float* __restrict__ Ip) {
    int bid = blockIdx.x;            // b*80 + cq*20 + hb
    int hb  = bid % NHB;
    int cq  = (bid / NHB) & 3;
    int b   = bid / (NHB * 4);
    int c0  = cq * 64;
    int t   = threadIdx.x;

    __shared__ float tile[64][161];
    __shared__ float segsum[64][5];

    int seg = t >> 6;        // 0..3
    int row = t & 63;        // 0..63

    f32x4 csum[10];
    #pragma unroll
    for (int it = 0; it < 10; ++it) csum[it] = (f32x4){0.f, 0.f, 0.f, 0.f};

    for (int hh = 0; hh < HB; ++hh) {
        int h = hb * HB + hh;
        __syncthreads();   // prev iteration's tile readers done

        // load row: 2560 float4 (64 channels x 160 w), coalesced, NT
        #pragma unroll
        for (int it = 0; it < 10; ++it) {
            int vid = it * 256 + t;              // 0..2559
            int c_l = vid / 40;
            int wq  = vid - c_l * 40;            // float4 index within row
            f32x4 v = __builtin_nontemporal_load(
                (const f32x4*)(fm + (((size_t)(b * CC + c0 + c_l)) * HFD + h) * WFD + wq * 4));
            tile[c_l][wq * 4 + 0] = v.x;
            tile[c_l][wq * 4 + 1] = v.y;
            tile[c_l][wq * 4 + 2] = v.z;
            tile[c_l][wq * 4 + 3] = v.w;
        }
        __syncthreads();

        // 4-segment parallel w-scan (seg = 40 elements)
        {
            float s = 0.f;
            int w0 = seg * 40;
            #pragma unroll 8
            for (int k = 0; k < 40; ++k) {
                s += tile[row][w0 + k];
                tile[row][w0 + k] = s;
            }
            segsum[row][seg] = s;
        }
        __syncthreads();
        if (t < 64) {
            float a0 = segsum[t][0];
            float a1 = a0 + segsum[t][1];
            float a2 = a1 + segsum[t][2];
            segsum[t][1] = a0;
            segsum[t][2] = a1;
            segsum[t][3] = a2;
        }
        __syncthreads();
        if (seg > 0) {
            float off = segsum[row][seg];
            int w0 = seg * 40;
            #pragma unroll 8
            for (int k = 0; k < 40; ++k) tile[row][w0 + k] += off;
        }
        __syncthreads();

        // transposed read + running column sum + store
        size_t obase = (((size_t)b * HFD + h) * WFD) * CC + c0;
        #pragma unroll
        for (int it = 0; it < 10; ++it) {
            int vid = it * 256 + t;
            int w   = vid >> 4;        // 0..159
            int cg  = vid & 15;        // c = 4*cg
            f32x4 cur;
            cur.x = tile[cg * 4 + 0][w];
            cur.y = tile[cg * 4 + 1][w];
            cur.z = tile[cg * 4 + 2][w];
            cur.w = tile[cg * 4 + 3][w];
            csum[it] += cur;
            *(f32x4*)(Ip + obase + (size_t)w * CC + cg * 4) = csum[it];
        }
    }
}

// ---------------------------------------------------------------------------
// K2': block-offset exclusive scan.  O[b][hb][w][c] = sum of block totals of
// all h-blocks before hb; block total of k = Ip[b][8k+7][w][c].
// One WG per (b,w), thread = c.  26 MB read + 26 MB write (tiny).
// ---------------------------------------------------------------------------
__global__ __launch_bounds__(256) void k2_offsets(const float* __restrict__ Ip,
                                                  float* __restrict__ O) {
    int w = blockIdx.x % WFD;
    int b = blockIdx.x / WFD;
    int c = threadIdx.x;
    float run = 0.f;
    #pragma unroll
    for (int hb = 0; hb < NHB; ++hb) {
        O[(((size_t)b * NHB + hb) * WFD + w) * CC + c] = run;
        run += Ip[(((size_t)b * HFD + (hb * HB + HB - 1)) * WFD + w) * CC + c];
    }
}

// ---------------------------------------------------------------------------
// K3: fused gather + GEMM, 512 threads (8 waves).
// bn swizzled so image b == XCD id.  Corner value = Ip(r,·) + O(r>>3,·):
// 8 fat loads per cell (4 base from L3, 4 offsets from L2-hot 26 MB array).
// Gather: wave wv owns cells wv*6+k (k=0..5); wave 0 additionally cell 48.
// GEMM: wave wv owns o in [wv*32, wv*32+32): acc[2][4], 64 MFMA/wave.
// Epilogue: LDS-staged coalesced f32x4 NT stores.
// ---------------------------------------------------------------------------
#define PB_STRIDE 264   // bf16 elems; 528 B row

__global__ __launch_bounds__(512, 4) void k3_gather_gemm(
        const float* __restrict__ Ip, const float* __restrict__ O,
        const __hip_bfloat16* __restrict__ Wb,
        const float* __restrict__ bias, const float* __restrict__ bboxes,
        const int* __restrict__ ih_p, const int* __restrict__ iw_p,
        float* __restrict__ out) {
    int bid = blockIdx.x;
    int bn  = ((bid & 7) << 7) | (bid >> 3);   // image = bid&7 -> one image per XCD
    int b   = bn >> 7;
    int t   = threadIdx.x;
    const int lane = t & 63;
    const int wv   = t >> 6;     // 0..7

    __shared__ __align__(16) __hip_bfloat16 Pb[64 * PB_STRIDE];   // 33 KB
    float* stage = (float*)Pb;   // reused after GEMM: 128 o x 49 cells = 25 KB

    float bx1 = bboxes[bn * 4 + 0];
    float by1 = bboxes[bn * 4 + 1];
    float bx2 = bboxes[bn * 4 + 2];
    float by2 = bboxes[bn * 4 + 3];
    float sx = (float)WFD / (float)iw_p[0];
    float sy = (float)HFD / (float)ih_p[0];

    int x1 = min(max((int)floorf(bx1 * sx), 0), WFD - 1);
    int y1 = min(max((int)floorf(by1 * sy), 0), HFD - 1);
    int x2 = min(max((int)floorf(bx2 * sx), x1 + 1), WFD);
    int y2 = min(max((int)floorf(by2 * sy), y1 + 1), HFD);
    int Lx = x2 - x1, Ly = y2 - y1;

    // ---- gather phase: branch-free fat loads, 49 cells exactly ----
    {
        const float* Ibl = Ip + (size_t)b * HFD * WFD * CC + 4 * lane;
        const float* Obl = O + (size_t)b * NHB * WFD * CC + 4 * lane;
        unsigned short* pbs = (unsigned short*)Pb;

#define GATHER_CELL(cellv)                                                       \
        {                                                                        \
            int cell = (cellv);                                                  \
            int i_ = cell / SS, j_ = cell % SS;                                  \
            int rs_ = y1 + (i_ * Ly) / SS;                                       \
            int re_ = y1 + ((i_ + 1) * Ly + SS - 1) / SS;                        \
            int cs_ = x1 + (j_ * Lx) / SS;                                       \
            int ce_ = x1 + ((j_ + 1) * Lx + SS - 1) / SS;                        \
            int r1 = re_ - 1;                                                    \
            int r0 = max(rs_ - 1, 0);                                            \
            int c1 = ce_ - 1;                                                    \
            int c0 = max(cs_ - 1, 0);                                            \
            int hb1 = r1 >> 3, hb0 = r0 >> 3;                                    \
            float rm = (rs_ > 0) ? 1.f : 0.f;                                    \
            float cm = (cs_ > 0) ? 1.f : 0.f;                                    \
            f32x4 br = *(const f32x4*)(Ibl + ((size_t)(r1 * WFD + c1)) * CC)     \
                     + *(const f32x4*)(Obl + ((size_t)(hb1 * WFD + c1)) * CC);   \
            f32x4 tr = *(const f32x4*)(Ibl + ((size_t)(r0 * WFD + c1)) * CC)     \
                     + *(const f32x4*)(Obl + ((size_t)(hb0 * WFD + c1)) * CC);   \
            f32x4 bl = *(const f32x4*)(Ibl + ((size_t)(r1 * WFD + c0)) * CC)     \
                     + *(const f32x4*)(Obl + ((size_t)(hb1 * WFD + c0)) * CC);   \
            f32x4 tl = *(const f32x4*)(Ibl + ((size_t)(r0 * WFD + c0)) * CC)     \
                     + *(const f32x4*)(Obl + ((size_t)(hb0 * WFD + c0)) * CC);   \
            f32x4 s = (br - tr * rm) - (bl - tl * rm) * cm;                      \
            float inv = 1.f / ((float)(re_ - rs_) * (float)(ce_ - cs_));         \
            ushort4 pk;                                                          \
            {                                                                    \
                __hip_bfloat16 h0 = __float2bfloat16(s.x * inv);                 \
                __hip_bfloat16 h1 = __float2bfloat16(s.y * inv);                 \
                __hip_bfloat16 h2 = __float2bfloat16(s.z * inv);                 \
                __hip_bfloat16 h3 = __float2bfloat16(s.w * inv);                 \
                pk.x = *(unsigned short*)&h0;                                    \
                pk.y = *(unsigned short*)&h1;                                    \
                pk.z = *(unsigned short*)&h2;                                    \
                pk.w = *(unsigned short*)&h3;                                    \
            }                                                                    \
            *(ushort4*)(pbs + cell * PB_STRIDE + 4 * lane) = pk;                 \
        }

        #pragma unroll
        for (int k = 0; k < 6; ++k) GATHER_CELL(wv * 6 + k);
        if (wv == 0) GATHER_CELL(48);
#undef GATHER_CELL
    }
    __syncthreads();

    // ---- GEMM phase: wave wv owns o in [wv*32, wv*32+32) ----
    const int ln   = lane & 15;
    const int quad = lane >> 4;
    const int ob0  = wv * 32;

    f32x4 z = {0.f, 0.f, 0.f, 0.f};
    f32x4 acc[2][4];
    #pragma unroll
    for (int mt = 0; mt < 2; ++mt)
        #pragma unroll
        for (int nt = 0; nt < 4; ++nt) acc[mt][nt] = z;

    {
        const short* A = (const short*)Wb;
        #pragma unroll
        for (int k0 = 0; k0 < CC; k0 += 32) {
            short8 a[2], bf[4];
            #pragma unroll
            for (int mt = 0; mt < 2; ++mt)
                a[mt] = *(const short8*)(A + (ob0 + mt * 16 + ln) * CC + k0 + quad * 8);
            #pragma unroll
            for (int nt = 0; nt < 4; ++nt)
                bf[nt] = *(const short8*)((const short*)Pb + (nt * 16 + ln) * PB_STRIDE + k0 + quad * 8);
            #pragma unroll
            for (int mt = 0; mt < 2; ++mt)
                #pragma unroll
                for (int nt = 0; nt < 4; ++nt)
                    acc[mt][nt] = __builtin_amdgcn_mfma_f32_16x16x32_bf16(a[mt], bf[nt], acc[mt][nt], 0, 0, 0);
        }
    }

    // ---- epilogue: LDS-staged, coalesced f32x4 NT stores ----
    size_t obase = (size_t)bn * CC * 49;
    #pragma unroll
    for (int half = 0; half < 2; ++half) {
        __syncthreads();   // half0: GEMM reads of Pb done; half1: copy0 done
        if ((wv >> 2) == half) {
            int ob0l = (wv & 3) * 32;      // o offset within this half
            #pragma unroll
            for (int mt = 0; mt < 2; ++mt) {
                f32x4 bv = *(const f32x4*)(bias + ob0 + mt * 16 + quad * 4);
                #pragma unroll
                for (int nt = 0; nt < 4; ++nt) {
                    int cell = nt * 16 + ln;
                    if (cell < 49) {
                        #pragma unroll
                        for (int reg = 0; reg < 4; ++reg) {
                            int ol = ob0l + mt * 16 + quad * 4 + reg;
                            stage[ol * 49 + cell] = acc[mt][nt][reg] + bv[reg];
                        }
                    }
                }
            }
        }
        __syncthreads();
        const f32x4* sv = (const f32x4*)stage;
        float* gbase = out + obase + (size_t)half * (128 * 49);
        for (int i = t; i < (128 * 49) / 4; i += 512) {
            __builtin_nontemporal_store(sv[i], (f32x4*)(gbase + 4 * i));
        }
    }

    if (t == 0) {
        __builtin_nontemporal_store((bx2 - bx1) * (by2 - by1), &out[REGION_OUT_ELEMS + bn]);
    }
}

// ---------------------------------------------------------------------------
extern "C" void kernel_launch(void* const* d_in, const int* in_sizes, int n_in,
                              void* d_out, int out_size, void* d_ws, size_t ws_size,
                              hipStream_t stream) {
    const float* fm     = (const float*)d_in[0];
    const float* bboxes = (const float*)d_in[1];
    const float* W      = (const float*)d_in[2];
    const float* bias   = (const float*)d_in[3];
    const int*   ih     = (const int*)d_in[4];
    const int*   iw     = (const int*)d_in[5];
    float* out = (float*)d_out;

    __hip_bfloat16* Wb = (__hip_bfloat16*)d_ws;                    // 256*256 bf16 = 128 KB
    float* Ip = (float*)((char*)d_ws + (size_t)CC * CC * 2 + 256); // partial integral, c-fastest
    Ip = (float*)(((uintptr_t)Ip + 1023) & ~(uintptr_t)1023);
    float* O = (float*)((char*)Ip + (size_t)BB * HFD * WFD * CC * 4);  // block offsets, 26 MB
    O = (float*)(((uintptr_t)O + 1023) & ~(uintptr_t)1023);

    k0_convert_w<<<CC, 256, 0, stream>>>(W, Wb);
    k1_rowscan_block<<<BB * 4 * NHB, 256, 0, stream>>>(fm, Ip);
    k2_offsets<<<BB * WFD, 256, 0, stream>>>(Ip, O);
    k3_gather_gemm<<<BB * NN, 512, 0, stream>>>(Ip, O, Wb, bias, bboxes, ih, iw, out);
}

// Round 7
// 390.288 us; speedup vs baseline: 1.2353x; 1.0146x over previous
//
#include <hip/hip_runtime.h>
#include <hip/hip_bf16.h>

// Problem constants
#define BB 8
#define NN 128
#define CC 256
#define HFD 160
#define WFD 160
#define SS 7
#define HB 8                 // h-block size for hierarchical integral
#define NHB (HFD / HB)       // 20 blocks
#define REGION_OUT_ELEMS (8*128*256*49)   // 12,845,056

typedef short short8 __attribute__((ext_vector_type(8)));
typedef float f32x4  __attribute__((ext_vector_type(4)));

// ---------------------------------------------------------------------------
// K0: convert proj_w [o][c] fp32 -> bf16, row-major (A-operand friendly).
// ---------------------------------------------------------------------------
__global__ __launch_bounds__(256) void k0_convert_w(const float* __restrict__ W,
                                                    __hip_bfloat16* __restrict__ Wb) {
    int o = blockIdx.x;
    int c = threadIdx.x;
    Wb[o * CC + c] = __float2bfloat16(W[o * CC + c]);
}

// ---------------------------------------------------------------------------
// K1': fused transpose + w-cumsum + within-8-row-block h-cumsum.
//   in : fm[b][c][h][w]   (w fastest)
//   out: Ip[b][h][w][c]   (c fastest); Ip = w-prefix + h-prefix within block
// WG owns (b, c-EIGHTH of 32 channels, h-block of 8 rows), 128 threads.
// 1280 WGs, 21 KB LDS -> 5 co-resident blocks/CU (vs 2.5 at 64-ch tiles):
// barrier stalls now hidden by cross-block overlap. Running column sum in
// 10 x f32x4 registers per thread.
// ---------------------------------------------------------------------------
__global__ __launch_bounds__(128) void k1_rowscan_block(const float* __restrict__ fm,
                                                        float* __restrict__ Ip) {
    int bid = blockIdx.x;            // b*160 + c8*20 + hb
    int hb  = bid % NHB;
    int c8  = (bid / NHB) & 7;
    int b   = bid / (NHB * 8);
    int c0  = c8 * 32;
    int t   = threadIdx.x;

    __shared__ float tile[32][161];
    __shared__ float segsum[32][5];

    int seg = t >> 5;        // 0..3
    int row = t & 31;        // 0..31

    f32x4 csum[10];
    #pragma unroll
    for (int it = 0; it < 10; ++it) csum[it] = (f32x4){0.f, 0.f, 0.f, 0.f};

    for (int hh = 0; hh < HB; ++hh) {
        int h = hb * HB + hh;
        __syncthreads();   // prev iteration's tile readers done

        // load row: 1280 float4 (32 channels x 160 w), coalesced, NT
        #pragma unroll
        for (int it = 0; it < 10; ++it) {
            int vid = it * 128 + t;              // 0..1279
            int c_l = vid / 40;                  // 0..31
            int wq  = vid - c_l * 40;            // float4 index within row
            f32x4 v = __builtin_nontemporal_load(
                (const f32x4*)(fm + (((size_t)(b * CC + c0 + c_l)) * HFD + h) * WFD + wq * 4));
            tile[c_l][wq * 4 + 0] = v.x;
            tile[c_l][wq * 4 + 1] = v.y;
            tile[c_l][wq * 4 + 2] = v.z;
            tile[c_l][wq * 4 + 3] = v.w;
        }
        __syncthreads();

        // 4-segment parallel w-scan (seg = 40 elements), all 128 lanes active
        {
            float s = 0.f;
            int w0 = seg * 40;
            #pragma unroll 8
            for (int k = 0; k < 40; ++k) {
                s += tile[row][w0 + k];
                tile[row][w0 + k] = s;
            }
            segsum[row][seg] = s;
        }
        __syncthreads();
        if (t < 32) {
            float a0 = segsum[t][0];
            float a1 = a0 + segsum[t][1];
            float a2 = a1 + segsum[t][2];
            segsum[t][1] = a0;
            segsum[t][2] = a1;
            segsum[t][3] = a2;
        }
        __syncthreads();
        if (seg > 0) {
            float off = segsum[row][seg];
            int w0 = seg * 40;
            #pragma unroll 8
            for (int k = 0; k < 40; ++k) tile[row][w0 + k] += off;
        }
        __syncthreads();

        // transposed read + running column sum + store
        size_t obase = (((size_t)b * HFD + h) * WFD) * CC + c0;
        #pragma unroll
        for (int it = 0; it < 10; ++it) {
            int vid = it * 128 + t;
            int w   = vid >> 3;        // 0..159
            int cg  = vid & 7;         // c = 4*cg within the 32-ch tile
            f32x4 cur;
            cur.x = tile[cg * 4 + 0][w];
            cur.y = tile[cg * 4 + 1][w];
            cur.z = tile[cg * 4 + 2][w];
            cur.w = tile[cg * 4 + 3][w];
            csum[it] += cur;
            *(f32x4*)(Ip + obase + (size_t)w * CC + cg * 4) = csum[it];
        }
    }
}

// ---------------------------------------------------------------------------
// K2': block-offset exclusive scan.  O[b][hb][w][c] = sum of block totals of
// all h-blocks before hb; block total of k = Ip[b][8k+7][w][c].
// One WG per (b,w), thread = c.  26 MB read + 26 MB write (tiny).
// ---------------------------------------------------------------------------
__global__ __launch_bounds__(256) void k2_offsets(const float* __restrict__ Ip,
                                                  float* __restrict__ O) {
    int w = blockIdx.x % WFD;
    int b = blockIdx.x / WFD;
    int c = threadIdx.x;
    float run = 0.f;
    #pragma unroll
    for (int hb = 0; hb < NHB; ++hb) {
        O[(((size_t)b * NHB + hb) * WFD + w) * CC + c] = run;
        run += Ip[(((size_t)b * HFD + (hb * HB + HB - 1)) * WFD + w) * CC + c];
    }
}

// ---------------------------------------------------------------------------
// K3: fused gather + GEMM, 512 threads (8 waves).
// bn swizzled so image b == XCD id.  Corner value = Ip(r,·) + O(r>>3,·).
// Gather: wave wv owns cells wv*6+k (k=0..5); wave 0 additionally cell 48.
// GEMM: wave wv owns o in [wv*32, wv*32+32): acc[2][4], 64 MFMA/wave.
// Epilogue: LDS-staged coalesced f32x4 NT stores.
// ---------------------------------------------------------------------------
#define PB_STRIDE 264   // bf16 elems; 528 B row

__global__ __launch_bounds__(512, 4) void k3_gather_gemm(
        const float* __restrict__ Ip, const float* __restrict__ O,
        const __hip_bfloat16* __restrict__ Wb,
        const float* __restrict__ bias, const float* __restrict__ bboxes,
        const int* __restrict__ ih_p, const int* __restrict__ iw_p,
        float* __restrict__ out) {
    int bid = blockIdx.x;
    int bn  = ((bid & 7) << 7) | (bid >> 3);   // image = bid&7 -> one image per XCD
    int b   = bn >> 7;
    int t   = threadIdx.x;
    const int lane = t & 63;
    const int wv   = t >> 6;     // 0..7

    __shared__ __align__(16) __hip_bfloat16 Pb[64 * PB_STRIDE];   // 33 KB
    float* stage = (float*)Pb;   // reused after GEMM: 128 o x 49 cells = 25 KB

    float bx1 = bboxes[bn * 4 + 0];
    float by1 = bboxes[bn * 4 + 1];
    float bx2 = bboxes[bn * 4 + 2];
    float by2 = bboxes[bn * 4 + 3];
    float sx = (float)WFD / (float)iw_p[0];
    float sy = (float)HFD / (float)ih_p[0];

    int x1 = min(max((int)floorf(bx1 * sx), 0), WFD - 1);
    int y1 = min(max((int)floorf(by1 * sy), 0), HFD - 1);
    int x2 = min(max((int)floorf(bx2 * sx), x1 + 1), WFD);
    int y2 = min(max((int)floorf(by2 * sy), y1 + 1), HFD);
    int Lx = x2 - x1, Ly = y2 - y1;

    // ---- gather phase: branch-free fat loads, 49 cells exactly ----
    {
        const float* Ibl = Ip + (size_t)b * HFD * WFD * CC + 4 * lane;
        const float* Obl = O + (size_t)b * NHB * WFD * CC + 4 * lane;
        unsigned short* pbs = (unsigned short*)Pb;

#define GATHER_CELL(cellv)                                                       \
        {                                                                        \
            int cell = (cellv);                                                  \
            int i_ = cell / SS, j_ = cell % SS;                                  \
            int rs_ = y1 + (i_ * Ly) / SS;                                       \
            int re_ = y1 + ((i_ + 1) * Ly + SS - 1) / SS;                        \
            int cs_ = x1 + (j_ * Lx) / SS;                                       \
            int ce_ = x1 + ((j_ + 1) * Lx + SS - 1) / SS;                        \
            int r1 = re_ - 1;                                                    \
            int r0 = max(rs_ - 1, 0);                                            \
            int c1 = ce_ - 1;                                                    \
            int c0 = max(cs_ - 1, 0);                                            \
            int hb1 = r1 >> 3, hb0 = r0 >> 3;                                    \
            float rm = (rs_ > 0) ? 1.f : 0.f;                                    \
            float cm = (cs_ > 0) ? 1.f : 0.f;                                    \
            f32x4 br = *(const f32x4*)(Ibl + ((size_t)(r1 * WFD + c1)) * CC)     \
                     + *(const f32x4*)(Obl + ((size_t)(hb1 * WFD + c1)) * CC);   \
            f32x4 tr = *(const f32x4*)(Ibl + ((size_t)(r0 * WFD + c1)) * CC)     \
                     + *(const f32x4*)(Obl + ((size_t)(hb0 * WFD + c1)) * CC);   \
            f32x4 bl = *(const f32x4*)(Ibl + ((size_t)(r1 * WFD + c0)) * CC)     \
                     + *(const f32x4*)(Obl + ((size_t)(hb1 * WFD + c0)) * CC);   \
            f32x4 tl = *(const f32x4*)(Ibl + ((size_t)(r0 * WFD + c0)) * CC)     \
                     + *(const f32x4*)(Obl + ((size_t)(hb0 * WFD + c0)) * CC);   \
            f32x4 s = (br - tr * rm) - (bl - tl * rm) * cm;                      \
            float inv = 1.f / ((float)(re_ - rs_) * (float)(ce_ - cs_));         \
            ushort4 pk;                                                          \
            {                                                                    \
                __hip_bfloat16 h0 = __float2bfloat16(s.x * inv);                 \
                __hip_bfloat16 h1 = __float2bfloat16(s.y * inv);                 \
                __hip_bfloat16 h2 = __float2bfloat16(s.z * inv);                 \
                __hip_bfloat16 h3 = __float2bfloat16(s.w * inv);                 \
                pk.x = *(unsigned short*)&h0;                                    \
                pk.y = *(unsigned short*)&h1;                                    \
                pk.z = *(unsigned short*)&h2;                                    \
                pk.w = *(unsigned short*)&h3;                                    \
            }                                                                    \
            *(ushort4*)(pbs + cell * PB_STRIDE + 4 * lane) = pk;                 \
        }

        #pragma unroll
        for (int k = 0; k < 6; ++k) GATHER_CELL(wv * 6 + k);
        if (wv == 0) GATHER_CELL(48);
#undef GATHER_CELL
    }
    __syncthreads();

    // ---- GEMM phase: wave wv owns o in [wv*32, wv*32+32) ----
    const int ln   = lane & 15;
    const int quad = lane >> 4;
    const int ob0  = wv * 32;

    f32x4 z = {0.f, 0.f, 0.f, 0.f};
    f32x4 acc[2][4];
    #pragma unroll
    for (int mt = 0; mt < 2; ++mt)
        #pragma unroll
        for (int nt = 0; nt < 4; ++nt) acc[mt][nt] = z;

    {
        const short* A = (const short*)Wb;
        #pragma unroll
        for (int k0 = 0; k0 < CC; k0 += 32) {
            short8 a[2], bf[4];
            #pragma unroll
            for (int mt = 0; mt < 2; ++mt)
                a[mt] = *(const short8*)(A + (ob0 + mt * 16 + ln) * CC + k0 + quad * 8);
            #pragma unroll
            for (int nt = 0; nt < 4; ++nt)
                bf[nt] = *(const short8*)((const short*)Pb + (nt * 16 + ln) * PB_STRIDE + k0 + quad * 8);
            #pragma unroll
            for (int mt = 0; mt < 2; ++mt)
                #pragma unroll
                for (int nt = 0; nt < 4; ++nt)
                    acc[mt][nt] = __builtin_amdgcn_mfma_f32_16x16x32_bf16(a[mt], bf[nt], acc[mt][nt], 0, 0, 0);
        }
    }

    // ---- epilogue: LDS-staged, coalesced f32x4 NT stores ----
    size_t obase = (size_t)bn * CC * 49;
    #pragma unroll
    for (int half = 0; half < 2; ++half) {
        __syncthreads();   // half0: GEMM reads of Pb done; half1: copy0 done
        if ((wv >> 2) == half) {
            int ob0l = (wv & 3) * 32;      // o offset within this half
            #pragma unroll
            for (int mt = 0; mt < 2; ++mt) {
                f32x4 bv = *(const f32x4*)(bias + ob0 + mt * 16 + quad * 4);
                #pragma unroll
                for (int nt = 0; nt < 4; ++nt) {
                    int cell = nt * 16 + ln;
                    if (cell < 49) {
                        #pragma unroll
                        for (int reg = 0; reg < 4; ++reg) {
                            int ol = ob0l + mt * 16 + quad * 4 + reg;
                            stage[ol * 49 + cell] = acc[mt][nt][reg] + bv[reg];
                        }
                    }
                }
            }
        }
        __syncthreads();
        const f32x4* sv = (const f32x4*)stage;
        float* gbase = out + obase + (size_t)half * (128 * 49);
        for (int i = t; i < (128 * 49) / 4; i += 512) {
            __builtin_nontemporal_store(sv[i], (f32x4*)(gbase + 4 * i));
        }
    }

    if (t == 0) {
        __builtin_nontemporal_store((bx2 - bx1) * (by2 - by1), &out[REGION_OUT_ELEMS + bn]);
    }
}

// ---------------------------------------------------------------------------
extern "C" void kernel_launch(void* const* d_in, const int* in_sizes, int n_in,
                              void* d_out, int out_size, void* d_ws, size_t ws_size,
                              hipStream_t stream) {
    const float* fm     = (const float*)d_in[0];
    const float* bboxes = (const float*)d_in[1];
    const float* W      = (const float*)d_in[2];
    const float* bias   = (const float*)d_in[3];
    const int*   ih     = (const int*)d_in[4];
    const int*   iw     = (const int*)d_in[5];
    float* out = (float*)d_out;

    __hip_bfloat16* Wb = (__hip_bfloat16*)d_ws;                    // 256*256 bf16 = 128 KB
    float* Ip = (float*)((char*)d_ws + (size_t)CC * CC * 2 + 256); // partial integral, c-fastest
    Ip = (float*)(((uintptr_t)Ip + 1023) & ~(uintptr_t)1023);
    float* O = (float*)((char*)Ip + (size_t)BB * HFD * WFD * CC * 4);  // block offsets, 26 MB
    O = (float*)(((uintptr_t)O + 1023) & ~(uintptr_t)1023);

    k0_convert_w<<<CC, 256, 0, stream>>>(W, Wb);
    k1_rowscan_block<<<BB * 8 * NHB, 128, 0, stream>>>(fm, Ip);
    k2_offsets<<<BB * WFD, 256, 0, stream>>>(Ip, O);
    k3_gather_gemm<<<BB * NN, 512, 0, stream>>>(Ip, O, Wb, bias, bboxes, ih, iw, out);
}

// Round 8
// 380.945 us; speedup vs baseline: 1.2656x; 1.0245x over previous
//
#include <hip/hip_runtime.h>
#include <hip/hip_bf16.h>

// Problem constants
#define BB 8
#define NN 128
#define CC 256
#define HFD 160
#define WFD 160
#define SS 7
#define HB 8                 // h-block size for hierarchical integral
#define NHB (HFD / HB)       // 20 blocks
#define REGION_OUT_ELEMS (8*128*256*49)   // 12,845,056

typedef short short8 __attribute__((ext_vector_type(8)));
typedef float f32x4  __attribute__((ext_vector_type(4)));

// ---------------------------------------------------------------------------
// K0: convert proj_w [o][c] fp32 -> bf16, row-major (A-operand friendly).
// ---------------------------------------------------------------------------
__global__ __launch_bounds__(256) void k0_convert_w(const float* __restrict__ W,
                                                    __hip_bfloat16* __restrict__ Wb) {
    int o = blockIdx.x;
    int c = threadIdx.x;
    Wb[o * CC + c] = __float2bfloat16(W[o * CC + c]);
}

// ---------------------------------------------------------------------------
// K1': fused transpose + w-cumsum + within-8-row-block h-cumsum.
//   in : fm[b][c][h][w]   (w fastest)
//   out: Ip[b][h][w][c]   (c fastest); Ip = w-prefix + h-prefix within block
// WG owns (b, c-eighth of 32 channels, h-block of 8 rows), 128 threads.
// Scan is REGISTER-based: 40 independent ds_read_b32 (pipelined) -> serial
// VALU scan (~160 cy) -> fixup+writeback. Replaces the old 40-deep serial
// LDS read-add-write chain (~5000 cy/row) that dominated K1.
// ---------------------------------------------------------------------------
__global__ __launch_bounds__(128) void k1_rowscan_block(const float* __restrict__ fm,
                                                        float* __restrict__ Ip) {
    int bid = blockIdx.x;            // b*160 + c8*20 + hb
    int hb  = bid % NHB;
    int c8  = (bid / NHB) & 7;
    int b   = bid / (NHB * 8);
    int c0  = c8 * 32;
    int t   = threadIdx.x;

    __shared__ float tile[32][161];
    __shared__ float segsum[32][5];

    int seg = t >> 5;        // 0..3
    int row = t & 31;        // 0..31
    const int w0 = seg * 40;

    f32x4 csum[10];
    #pragma unroll
    for (int it = 0; it < 10; ++it) csum[it] = (f32x4){0.f, 0.f, 0.f, 0.f};

    for (int hh = 0; hh < HB; ++hh) {
        int h = hb * HB + hh;
        __syncthreads();   // prev iteration's tile readers done

        // load row: 1280 float4 (32 channels x 160 w), coalesced, NT
        #pragma unroll
        for (int it = 0; it < 10; ++it) {
            int vid = it * 128 + t;              // 0..1279
            int c_l = vid / 40;                  // 0..31
            int wq  = vid - c_l * 40;            // float4 index within row
            f32x4 v = __builtin_nontemporal_load(
                (const f32x4*)(fm + (((size_t)(b * CC + c0 + c_l)) * HFD + h) * WFD + wq * 4));
            tile[c_l][wq * 4 + 0] = v.x;
            tile[c_l][wq * 4 + 1] = v.y;
            tile[c_l][wq * 4 + 2] = v.z;
            tile[c_l][wq * 4 + 3] = v.w;
        }
        __syncthreads();

        // register scan: 40 independent LDS reads -> serial VALU scan
        float v[40];
        #pragma unroll
        for (int k = 0; k < 40; ++k) v[k] = tile[row][w0 + k];
        #pragma unroll
        for (int k = 1; k < 40; ++k) v[k] += v[k - 1];
        segsum[row][seg] = v[39];
        __syncthreads();

        // per-thread segment offset (no serial sub-phase, no extra barrier)
        float off = 0.f;
        if (seg > 0) off += segsum[row][0];
        if (seg > 1) off += segsum[row][1];
        if (seg > 2) off += segsum[row][2];
        #pragma unroll
        for (int k = 0; k < 40; ++k) tile[row][w0 + k] = v[k] + off;
        __syncthreads();

        // transposed read + running column sum + store
        size_t obase = (((size_t)b * HFD + h) * WFD) * CC + c0;
        #pragma unroll
        for (int it = 0; it < 10; ++it) {
            int vid = it * 128 + t;
            int w   = vid >> 3;        // 0..159
            int cg  = vid & 7;         // c = 4*cg within the 32-ch tile
            f32x4 cur;
            cur.x = tile[cg * 4 + 0][w];
            cur.y = tile[cg * 4 + 1][w];
            cur.z = tile[cg * 4 + 2][w];
            cur.w = tile[cg * 4 + 3][w];
            csum[it] += cur;
            *(f32x4*)(Ip + obase + (size_t)w * CC + cg * 4) = csum[it];
        }
    }
}

// ---------------------------------------------------------------------------
// K2': block-offset exclusive scan.  O[b][hb][w][c] = sum of block totals of
// all h-blocks before hb; block total of k = Ip[b][8k+7][w][c].
// One WG per (b,w), thread = c.  26 MB read + 26 MB write (tiny).
// ---------------------------------------------------------------------------
__global__ __launch_bounds__(256) void k2_offsets(const float* __restrict__ Ip,
                                                  float* __restrict__ O) {
    int w = blockIdx.x % WFD;
    int b = blockIdx.x / WFD;
    int c = threadIdx.x;
    float run = 0.f;
    #pragma unroll
    for (int hb = 0; hb < NHB; ++hb) {
        O[(((size_t)b * NHB + hb) * WFD + w) * CC + c] = run;
        run += Ip[(((size_t)b * HFD + (hb * HB + HB - 1)) * WFD + w) * CC + c];
    }
}

// ---------------------------------------------------------------------------
// K3: fused gather + GEMM, 512 threads (8 waves).
// bn swizzled so image b == XCD id.  Corner value = Ip(r,·) + O(r>>3,·).
// Gather: wave wv owns cells wv*6+k (k=0..5); wave 0 additionally cell 48.
// GEMM: wave wv owns o in [wv*32, wv*32+32): acc[2][4], 64 MFMA/wave.
// Epilogue: LDS-staged coalesced f32x4 NT stores.
// ---------------------------------------------------------------------------
#define PB_STRIDE 264   // bf16 elems; 528 B row

__global__ __launch_bounds__(512, 4) void k3_gather_gemm(
        const float* __restrict__ Ip, const float* __restrict__ O,
        const __hip_bfloat16* __restrict__ Wb,
        const float* __restrict__ bias, const float* __restrict__ bboxes,
        const int* __restrict__ ih_p, const int* __restrict__ iw_p,
        float* __restrict__ out) {
    int bid = blockIdx.x;
    int bn  = ((bid & 7) << 7) | (bid >> 3);   // image = bid&7 -> one image per XCD
    int b   = bn >> 7;
    int t   = threadIdx.x;
    const int lane = t & 63;
    const int wv   = t >> 6;     // 0..7

    __shared__ __align__(16) __hip_bfloat16 Pb[64 * PB_STRIDE];   // 33 KB
    float* stage = (float*)Pb;   // reused after GEMM: 128 o x 49 cells = 25 KB

    float bx1 = bboxes[bn * 4 + 0];
    float by1 = bboxes[bn * 4 + 1];
    float bx2 = bboxes[bn * 4 + 2];
    float by2 = bboxes[bn * 4 + 3];
    float sx = (float)WFD / (float)iw_p[0];
    float sy = (float)HFD / (float)ih_p[0];

    int x1 = min(max((int)floorf(bx1 * sx), 0), WFD - 1);
    int y1 = min(max((int)floorf(by1 * sy), 0), HFD - 1);
    int x2 = min(max((int)floorf(bx2 * sx), x1 + 1), WFD);
    int y2 = min(max((int)floorf(by2 * sy), y1 + 1), HFD);
    int Lx = x2 - x1, Ly = y2 - y1;

    // ---- gather phase: branch-free fat loads, 49 cells exactly ----
    {
        const float* Ibl = Ip + (size_t)b * HFD * WFD * CC + 4 * lane;
        const float* Obl = O + (size_t)b * NHB * WFD * CC + 4 * lane;
        unsigned short* pbs = (unsigned short*)Pb;

#define GATHER_CELL(cellv)                                                       \
        {                                                                        \
            int cell = (cellv);                                                  \
            int i_ = cell / SS, j_ = cell % SS;                                  \
            int rs_ = y1 + (i_ * Ly) / SS;                                       \
            int re_ = y1 + ((i_ + 1) * Ly + SS - 1) / SS;                        \
            int cs_ = x1 + (j_ * Lx) / SS;                                       \
            int ce_ = x1 + ((j_ + 1) * Lx + SS - 1) / SS;                        \
            int r1 = re_ - 1;                                                    \
            int r0 = max(rs_ - 1, 0);                                            \
            int c1 = ce_ - 1;                                                    \
            int c0 = max(cs_ - 1, 0);                                            \
            int hb1 = r1 >> 3, hb0 = r0 >> 3;                                    \
            float rm = (rs_ > 0) ? 1.f : 0.f;                                    \
            float cm = (cs_ > 0) ? 1.f : 0.f;                                    \
            f32x4 br = *(const f32x4*)(Ibl + ((size_t)(r1 * WFD + c1)) * CC)     \
                     + *(const f32x4*)(Obl + ((size_t)(hb1 * WFD + c1)) * CC);   \
            f32x4 tr = *(const f32x4*)(Ibl + ((size_t)(r0 * WFD + c1)) * CC)     \
                     + *(const f32x4*)(Obl + ((size_t)(hb0 * WFD + c1)) * CC);   \
            f32x4 bl = *(const f32x4*)(Ibl + ((size_t)(r1 * WFD + c0)) * CC)     \
                     + *(const f32x4*)(Obl + ((size_t)(hb1 * WFD + c0)) * CC);   \
            f32x4 tl = *(const f32x4*)(Ibl + ((size_t)(r0 * WFD + c0)) * CC)     \
                     + *(const f32x4*)(Obl + ((size_t)(hb0 * WFD + c0)) * CC);   \
            f32x4 s = (br - tr * rm) - (bl - tl * rm) * cm;                      \
            float inv = 1.f / ((float)(re_ - rs_) * (float)(ce_ - cs_));         \
            ushort4 pk;                                                          \
            {                                                                    \
                __hip_bfloat16 h0 = __float2bfloat16(s.x * inv);                 \
                __hip_bfloat16 h1 = __float2bfloat16(s.y * inv);                 \
                __hip_bfloat16 h2 = __float2bfloat16(s.z * inv);                 \
                __hip_bfloat16 h3 = __float2bfloat16(s.w * inv);                 \
                pk.x = *(unsigned short*)&h0;                                    \
                pk.y = *(unsigned short*)&h1;                                    \
                pk.z = *(unsigned short*)&h2;                                    \
                pk.w = *(unsigned short*)&h3;                                    \
            }                                                                    \
            *(ushort4*)(pbs + cell * PB_STRIDE + 4 * lane) = pk;                 \
        }

        #pragma unroll
        for (int k = 0; k < 6; ++k) GATHER_CELL(wv * 6 + k);
        if (wv == 0) GATHER_CELL(48);
#undef GATHER_CELL
    }
    __syncthreads();

    // ---- GEMM phase: wave wv owns o in [wv*32, wv*32+32) ----
    const int ln   = lane & 15;
    const int quad = lane >> 4;
    const int ob0  = wv * 32;

    f32x4 z = {0.f, 0.f, 0.f, 0.f};
    f32x4 acc[2][4];
    #pragma unroll
    for (int mt = 0; mt < 2; ++mt)
        #pragma unroll
        for (int nt = 0; nt < 4; ++nt) acc[mt][nt] = z;

    {
        const short* A = (const short*)Wb;
        #pragma unroll
        for (int k0 = 0; k0 < CC; k0 += 32) {
            short8 a[2], bf[4];
            #pragma unroll
            for (int mt = 0; mt < 2; ++mt)
                a[mt] = *(const short8*)(A + (ob0 + mt * 16 + ln) * CC + k0 + quad * 8);
            #pragma unroll
            for (int nt = 0; nt < 4; ++nt)
                bf[nt] = *(const short8*)((const short*)Pb + (nt * 16 + ln) * PB_STRIDE + k0 + quad * 8);
            #pragma unroll
            for (int mt = 0; mt < 2; ++mt)
                #pragma unroll
                for (int nt = 0; nt < 4; ++nt)
                    acc[mt][nt] = __builtin_amdgcn_mfma_f32_16x16x32_bf16(a[mt], bf[nt], acc[mt][nt], 0, 0, 0);
        }
    }

    // ---- epilogue: LDS-staged, coalesced f32x4 NT stores ----
    size_t obase = (size_t)bn * CC * 49;
    #pragma unroll
    for (int half = 0; half < 2; ++half) {
        __syncthreads();   // half0: GEMM reads of Pb done; half1: copy0 done
        if ((wv >> 2) == half) {
            int ob0l = (wv & 3) * 32;      // o offset within this half
            #pragma unroll
            for (int mt = 0; mt < 2; ++mt) {
                f32x4 bv = *(const f32x4*)(bias + ob0 + mt * 16 + quad * 4);
                #pragma unroll
                for (int nt = 0; nt < 4; ++nt) {
                    int cell = nt * 16 + ln;
                    if (cell < 49) {
                        #pragma unroll
                        for (int reg = 0; reg < 4; ++reg) {
                            int ol = ob0l + mt * 16 + quad * 4 + reg;
                            stage[ol * 49 + cell] = acc[mt][nt][reg] + bv[reg];
                        }
                    }
                }
            }
        }
        __syncthreads();
        const f32x4* sv = (const f32x4*)stage;
        float* gbase = out + obase + (size_t)half * (128 * 49);
        for (int i = t; i < (128 * 49) / 4; i += 512) {
            __builtin_nontemporal_store(sv[i], (f32x4*)(gbase + 4 * i));
        }
    }

    if (t == 0) {
        __builtin_nontemporal_store((bx2 - bx1) * (by2 - by1), &out[REGION_OUT_ELEMS + bn]);
    }
}

// ---------------------------------------------------------------------------
extern "C" void kernel_launch(void* const* d_in, const int* in_sizes, int n_in,
                              void* d_out, int out_size, void* d_ws, size_t ws_size,
                              hipStream_t stream) {
    const float* fm     = (const float*)d_in[0];
    const float* bboxes = (const float*)d_in[1];
    const float* W      = (const float*)d_in[2];
    const float* bias   = (const float*)d_in[3];
    const int*   ih     = (const int*)d_in[4];
    const int*   iw     = (const int*)d_in[5];
    float* out = (float*)d_out;

    __hip_bfloat16* Wb = (__hip_bfloat16*)d_ws;                    // 256*256 bf16 = 128 KB
    float* Ip = (float*)((char*)d_ws + (size_t)CC * CC * 2 + 256); // partial integral, c-fastest
    Ip = (float*)(((uintptr_t)Ip + 1023) & ~(uintptr_t)1023);
    float* O = (float*)((char*)Ip + (size_t)BB * HFD * WFD * CC * 4);  // block offsets, 26 MB
    O = (float*)(((uintptr_t)O + 1023) & ~(uintptr_t)1023);

    k0_convert_w<<<CC, 256, 0, stream>>>(W, Wb);
    k1_rowscan_block<<<BB * 8 * NHB, 128, 0, stream>>>(fm, Ip);
    k2_offsets<<<BB * WFD, 256, 0, stream>>>(Ip, O);
    k3_gather_gemm<<<BB * NN, 512, 0, stream>>>(Ip, O, Wb, bias, bboxes, ih, iw, out);
}